// Round 10
// baseline (52.273 us; speedup 1.0000x reference)
//
#include <hip/hip_runtime.h>
#include <hip/hip_fp16.h>
#include <math.h>

// N=20000, K=16, in_dim=128, out_dim=128, H1=H2=16
// Hermitian-reduced spectrum: e = v*16 + u, v=0..8, u=0..15  -> NE=144
// Spectra GEMM (MFMA fp16): C[20000 x 288] = feat(f16) @ B, B packed frag-order.
// MLP GEMM (MFMA bf16):     out[16 x 128] = P_bf16[16 x 288] @ Wp + b_mlp.
#define IN_DIM 128
#define NE 144
#define NCOL 288           // NE*2 half-columns
#define NT 18              // NCOL/16 N-tiles (spectra GEMM)
#define OUT_DIM 128
#define KNBR 16

typedef _Float16 f16x8 __attribute__((ext_vector_type(8)));
typedef short    bf16x8 __attribute__((ext_vector_type(8)));
typedef float    f32x4 __attribute__((ext_vector_type(4)));

__device__ __forceinline__ float2 cmul(float2 a, float2 b) {
    return make_float2(a.x * b.x - a.y * b.y, a.x * b.y + a.y * b.x);
}

__device__ __forceinline__ float2 h2f(unsigned int u) {
    return __half22float2(__builtin_bit_cast(__half2, u));
}

__device__ __forceinline__ unsigned int u4c(const uint4& v, int j) {
    return j == 0 ? v.x : j == 1 ? v.y : j == 2 ? v.z : v.w;
}

__device__ __forceinline__ unsigned short f2bf(float x) {
    unsigned int u = __float_as_uint(x);
    unsigned int r = (u + 0x7FFFu + ((u >> 16) & 1u)) >> 16;
    return (unsigned short)r;
}

// ---------------------------------------------------------------------------
// Merged prep (unchanged).
// Blocks 0..127 (row d): forward-DFT fold of W_aff -> Bp (fp16 frag order).
// Block 128: bias -> bf[288] f32.
// Blocks 129..272 (e=blk-129): IFFT2+Re+Hermitian fold of W_mlp -> Wp (bf16).
// ---------------------------------------------------------------------------
__global__ __launch_bounds__(256) void k_prep(
    const float* __restrict__ W_aff, const float* __restrict__ b_aff,
    const float* __restrict__ W_mlp,
    __half* __restrict__ Bp, float* __restrict__ bf,
    unsigned short* __restrict__ Wp)
{
    __shared__ float twc[16], tws[16];
    const int t = threadIdx.x;
    if (t < 16) {
        float a = (float)M_PI * (float)t / 8.0f;   // 2*pi*t/16
        twc[t] = cosf(a);
        tws[t] = sinf(a);
    }
    __syncthreads();

    if (blockIdx.x < 129) {
        const int e = t;
        if (e >= NE) return;
        const int u = e & 15, v = e >> 4;
        const float* src = (blockIdx.x == 128) ? b_aff
                                               : (W_aff + blockIdx.x * 256);
        float ar = 0.f, ai = 0.f;
        for (int rc = 0; rc < 256; ++rc) {
            int m = (u * (rc >> 4) + v * (rc & 15)) & 15;
            float x = src[rc];                      // uniform -> s_load
            ar = fmaf(x, twc[m], ar);
            ai = fmaf(x, -tws[m], ai);
        }
        if (blockIdx.x == 128) {
            bf[2 * e + 0] = ar;
            bf[2 * e + 1] = ai;
        } else {
            const int d = blockIdx.x;
            const int kt = d >> 5, kin = d & 31;
            const int lhi = (kin >> 3) * 16, i = kin & 7;
            const int c0 = 2 * e, c1 = 2 * e + 1;
            Bp[(((size_t)kt * NT + (c0 >> 4)) * 64 + lhi + (c0 & 15)) * 8 + i] =
                __float2half(ar);
            Bp[(((size_t)kt * NT + (c1 >> 4)) * 64 + lhi + (c1 & 15)) * 8 + i] =
                __float2half(ai);
        }
    } else {
        const int j = t;
        if (j >= 128) return;
        const int e = blockIdx.x - 129;            // 0..143
        const int u = e & 15, v = e >> 4;
        float A = 0.f, B = 0.f;
        for (int rc = 0; rc < 256; ++rc) {
            int m = (u * (rc >> 4) + v * (rc & 15)) & 15;
            float wv_ = W_mlp[rc * 128 + j];        // coalesced
            A = fmaf(wv_, twc[m], A);
            B = fmaf(wv_, tws[m], B);
        }
        const float s = ((v == 0) || (v == 8)) ? (1.0f / 256.0f)
                                               : (2.0f / 256.0f);
        const size_t base =
            (((size_t)v * 8 + (j >> 4)) * 64 + (u >> 2) * 16 + (j & 15)) * 8 +
            2 * (u & 3);
        Wp[base + 0] = f2bf(A * s);
        Wp[base + 1] = f2bf(-B * s);
    }
}

// ---------------------------------------------------------------------------
// Spectra GEMM (unchanged): fused f32->f16 A-load, 3-way nt-split.
// Grid 3750 x 64 threads. Block b: nodes (b/3)*16..+16, nt range (b%3)*6..+6.
// ---------------------------------------------------------------------------
__global__ __launch_bounds__(64) void k_spectra_mfma(
    const float* __restrict__ feat, const __half* __restrict__ Bp,
    const float* __restrict__ bf, __half* __restrict__ Fh)
{
    const int node0 = (blockIdx.x / 3) * 16;
    const int ntb   = (blockIdx.x % 3) * 6;
    const int lane  = threadIdx.x;
    const int row   = lane & 15, kg = lane >> 4;

    f16x8 a[4];
#pragma unroll
    for (int kt = 0; kt < 4; ++kt) {
        const float* p = &feat[(node0 + row) * IN_DIM + kt * 32 + kg * 8];
        const float4 fa = *(const float4*)p;
        const float4 fb = *(const float4*)(p + 4);
        f16x8 t = {(_Float16)fa.x, (_Float16)fa.y, (_Float16)fa.z,
                   (_Float16)fa.w, (_Float16)fb.x, (_Float16)fb.y,
                   (_Float16)fb.z, (_Float16)fb.w};
        a[kt] = t;
    }

#pragma unroll
    for (int t = 0; t < 6; ++t) {
        const int nt = ntb + t;
        f32x4 c = {0.f, 0.f, 0.f, 0.f};
#pragma unroll
        for (int kt = 0; kt < 4; ++kt) {
            const f16x8 b =
                *(const f16x8*)&Bp[(((size_t)kt * NT + nt) * 64 + lane) * 8];
            c = __builtin_amdgcn_mfma_f32_16x16x32_f16(a[kt], b, c, 0, 0, 0);
        }
        const int col = nt * 16 + row;
        const float bias = bf[col];
#pragma unroll
        for (int r = 0; r < 4; ++r) {
            const int nrow = kg * 4 + r;
            Fh[(size_t)(node0 + nrow) * NCOL + col] = __float2half(c[r] + bias);
        }
    }
}

// ---------------------------------------------------------------------------
// Gather + product + MFMA MLP v3. 16 nodes/block, 256 threads (4 waves).
// Product: wave w owns nodes 4w..4w+3. Lane (<36) prefetches ALL 16 neighbor
//   16B chunks (e = 4*lane..4*lane+3) in one burst -> one memory round-trip
//   per node; product tree identical (bit-identical result). P -> bf16 ->
//   LDS in MFMA-A fragment layout (padded).
// MLP: wave w owns cols [32w, 32w+32): 9 kt x 2 nt mfma_f32_16x16x32_bf16.
// ---------------------------------------------------------------------------
__global__ __launch_bounds__(256) void k_gather_mlp(
    const int* __restrict__ nbr, const __half* __restrict__ Fh,
    const unsigned short* __restrict__ Wp, const float* __restrict__ b_mlp,
    float* __restrict__ out)
{
    const int node0 = blockIdx.x * 16;
    const int tid  = threadIdx.x;
    const int lane = tid & 63;
    const int w    = __builtin_amdgcn_readfirstlane(tid >> 6);

    __shared__ unsigned short A_lds[9 * 4 * 136];   // 9.8 KB

    // ---- product phase: 4 nodes per wave, lanes 0..35 active
#pragma unroll
    for (int m = 0; m < 4; ++m) {
        const int gm = w * 4 + m;                     // block-local node 0..15
        const int* nrow = nbr + (node0 + gm) * KNBR;  // uniform -> s_load

        if (lane < 36) {
            uint4 f[16];
#pragma unroll
            for (int k = 0; k < 16; ++k)              // 16-deep prefetch
                f[k] = *(const uint4*)&Fh[(size_t)nrow[k] * NCOL + lane * 8];
#pragma unroll
            for (int j = 0; j < 4; ++j) {
                float2 c[16];
#pragma unroll
                for (int k = 0; k < 16; ++k) c[k] = h2f(u4c(f[k], j));
                float2 g[8];
#pragma unroll
                for (int k = 0; k < 8; ++k) g[k] = cmul(c[2 * k], c[2 * k + 1]);
#pragma unroll
                for (int k = 0; k < 4; ++k) g[k] = cmul(g[2 * k], g[2 * k + 1]);
                const float2 p = cmul(cmul(g[0], g[1]), cmul(g[2], g[3]));

                const int e = lane * 4 + j;           // 0..143
                const int u = e & 15, v = e >> 4;
                const int off =
                    ((v * 4 + (u >> 2)) * 136) + gm * 8 + 2 * (u & 3);
                *(ushort2*)&A_lds[off] = make_ushort2(f2bf(p.x), f2bf(p.y));
            }
        }
    }
    __syncthreads();

    // ---- MFMA MLP: wave w -> cols [32w, 32w+32)
    f32x4 c0 = {0.f, 0.f, 0.f, 0.f}, c1 = {0.f, 0.f, 0.f, 0.f};
#pragma unroll
    for (int kt = 0; kt < 9; ++kt) {
        const bf16x8 a =
            *(const bf16x8*)&A_lds[(kt * 4 + (lane >> 4)) * 136 + (lane & 15) * 8];
        const bf16x8 b0 = *(const bf16x8*)
            &Wp[(((size_t)kt * 8 + (w * 2 + 0)) * 64 + lane) * 8];
        const bf16x8 b1 = *(const bf16x8*)
            &Wp[(((size_t)kt * 8 + (w * 2 + 1)) * 64 + lane) * 8];
        c0 = __builtin_amdgcn_mfma_f32_16x16x32_bf16(a, b0, c0, 0, 0, 0);
        c1 = __builtin_amdgcn_mfma_f32_16x16x32_bf16(a, b1, c1, 0, 0, 0);
    }

    // ---- epilogue: + bias, store
    {
        const int col0 = (w * 2 + 0) * 16 + (lane & 15);
        const int col1 = (w * 2 + 1) * 16 + (lane & 15);
        const float bias0 = b_mlp[col0];
        const float bias1 = b_mlp[col1];
#pragma unroll
        for (int r = 0; r < 4; ++r) {
            const int row = (lane >> 4) * 4 + r;
            out[(node0 + row) * OUT_DIM + col0] = c0[r] + bias0;
            out[(node0 + row) * OUT_DIM + col1] = c1[r] + bias1;
        }
    }
}

extern "C" void kernel_launch(void* const* d_in, const int* in_sizes, int n_in,
                              void* d_out, int out_size, void* d_ws, size_t ws_size,
                              hipStream_t stream) {
    const float* feature   = (const float*)d_in[0];
    const int*   neighbors = (const int*)d_in[1];
    const float* W_aff     = (const float*)d_in[2];
    const float* b_aff     = (const float*)d_in[3];
    const float* W_mlp     = (const float*)d_in[4];
    const float* b_mlp     = (const float*)d_in[5];
    float*       out       = (float*)d_out;

    const int N = in_sizes[0] / IN_DIM;   // 20000

    // workspace layout
    __half*         Bp = (__half*)d_ws;                   // 36864 halfs
    float*          bf = (float*)(Bp + 36864);            // 288 f32
    unsigned short* Wp = (unsigned short*)(bf + 288);     // 36864 bf16
    __half*         Fh = (__half*)(Wp + 36864);           // N*288 (11.5 MB)

    k_prep<<<273, 256, 0, stream>>>(W_aff, b_aff, W_mlp, Bp, bf, Wp);
    k_spectra_mfma<<<3750, 64, 0, stream>>>(feature, Bp, bf, Fh);
    k_gather_mlp<<<N / 16, 256, 0, stream>>>(neighbors, Fh, Wp, b_mlp, out);
}

// Round 11
// 51.092 us; speedup vs baseline: 1.0231x; 1.0231x over previous
//
#include <hip/hip_runtime.h>
#include <hip/hip_fp16.h>
#include <math.h>

// N=20000, K=16, in_dim=128, out_dim=128, H1=H2=16
// Hermitian-reduced spectrum: e = v*16 + u, v=0..8, u=0..15  -> NE=144
// Spectra GEMM (MFMA fp16): planar cols (re=0..143, im=144..287), output
//   stored as half2 planes Fp[gg=e>>4][node][16 half2]  (9 planes x 1.28 MB).
// Gather: block=(node-tile, plane gg), bid%8 pins plane->XCD so random reads
//   are per-XCD-L2-resident. Partial P -> Pg in MFMA-A k-chunk layout.
// MLP GEMM (MFMA bf16): out[16x128] = Pg @ Wp + b_mlp (streaming, no LDS).
#define IN_DIM 128
#define NE 144
#define NT 18              // 18 col-tiles (9 re + 9 im)
#define OUT_DIM 128
#define KNBR 16

typedef _Float16 f16x8 __attribute__((ext_vector_type(8)));
typedef short    bf16x8 __attribute__((ext_vector_type(8)));
typedef float    f32x4 __attribute__((ext_vector_type(4)));

__device__ __forceinline__ float2 cmul(float2 a, float2 b) {
    return make_float2(a.x * b.x - a.y * b.y, a.x * b.y + a.y * b.x);
}

__device__ __forceinline__ float2 h2f(unsigned int u) {
    return __half22float2(__builtin_bit_cast(__half2, u));
}

__device__ __forceinline__ unsigned int u4c(const uint4& v, int j) {
    return j == 0 ? v.x : j == 1 ? v.y : j == 2 ? v.z : v.w;
}

__device__ __forceinline__ unsigned short f2bf(float x) {
    unsigned int u = __float_as_uint(x);
    unsigned int r = (u + 0x7FFFu + ((u >> 16) & 1u)) >> 16;
    return (unsigned short)r;
}

__device__ __forceinline__ unsigned int packbf(float x, float y) {
    return (unsigned int)f2bf(x) | ((unsigned int)f2bf(y) << 16);
}

// ---------------------------------------------------------------------------
// Merged prep.
// Blocks 0..127 (row d): forward-DFT fold of W_aff -> Bp, PLANAR cols:
//   col e (<144) = Re W_fft2[d][e], col 144+e = Im.
// Block 128: bias -> bf[288] f32 (same planar order).
// Blocks 129..272 (e=blk-129): IFFT2+Re+Hermitian fold of W_mlp -> Wp (bf16,
//   k = 2e + {0:re,1:im} -- unchanged from R8/R9).
// ---------------------------------------------------------------------------
__global__ __launch_bounds__(256) void k_prep(
    const float* __restrict__ W_aff, const float* __restrict__ b_aff,
    const float* __restrict__ W_mlp,
    __half* __restrict__ Bp, float* __restrict__ bf,
    unsigned short* __restrict__ Wp)
{
    __shared__ float twc[16], tws[16];
    const int t = threadIdx.x;
    if (t < 16) {
        float a = (float)M_PI * (float)t / 8.0f;   // 2*pi*t/16
        twc[t] = cosf(a);
        tws[t] = sinf(a);
    }
    __syncthreads();

    if (blockIdx.x < 129) {
        const int e = t;
        if (e >= NE) return;
        const int u = e & 15, v = e >> 4;
        const float* src = (blockIdx.x == 128) ? b_aff
                                               : (W_aff + blockIdx.x * 256);
        float ar = 0.f, ai = 0.f;
        for (int rc = 0; rc < 256; ++rc) {
            int m = (u * (rc >> 4) + v * (rc & 15)) & 15;
            float x = src[rc];                      // uniform -> s_load
            ar = fmaf(x, twc[m], ar);
            ai = fmaf(x, -tws[m], ai);
        }
        if (blockIdx.x == 128) {
            bf[e]      = ar;
            bf[NE + e] = ai;
        } else {
            const int d = blockIdx.x;
            const int kt = d >> 5, kin = d & 31;
            const int lhi = (kin >> 3) * 16, i = kin & 7;
            const int c0 = e, c1 = NE + e;         // planar re / im cols
            Bp[(((size_t)kt * NT + (c0 >> 4)) * 64 + lhi + (c0 & 15)) * 8 + i] =
                __float2half(ar);
            Bp[(((size_t)kt * NT + (c1 >> 4)) * 64 + lhi + (c1 & 15)) * 8 + i] =
                __float2half(ai);
        }
    } else {
        const int j = t;
        if (j >= 128) return;
        const int e = blockIdx.x - 129;            // 0..143
        const int u = e & 15, v = e >> 4;
        float A = 0.f, B = 0.f;
        for (int rc = 0; rc < 256; ++rc) {
            int m = (u * (rc >> 4) + v * (rc & 15)) & 15;
            float wv_ = W_mlp[rc * 128 + j];        // coalesced
            A = fmaf(wv_, twc[m], A);
            B = fmaf(wv_, tws[m], B);
        }
        const float s = ((v == 0) || (v == 8)) ? (1.0f / 256.0f)
                                               : (2.0f / 256.0f);
        const size_t base =
            (((size_t)v * 8 + (j >> 4)) * 64 + (u >> 2) * 16 + (j & 15)) * 8 +
            2 * (u & 3);
        Wp[base + 0] = f2bf(A * s);
        Wp[base + 1] = f2bf(-B * s);
    }
}

// ---------------------------------------------------------------------------
// Spectra GEMM: fused f32->f16 A-load, 3-way split over plane-pairs.
// Grid 3750 x 64. Block b: nodes (b/3)*16..+16, plane-pairs (b%3)*3..+3.
// Plane pair p: re from col-tile p, im from col-tile p+9; lane writes the
// half2 (re,im) of element e = p*16 + row for 4 node-rows.
// ---------------------------------------------------------------------------
__global__ __launch_bounds__(64) void k_spectra_mfma(
    const float* __restrict__ feat, const __half* __restrict__ Bp,
    const float* __restrict__ bf, __half2* __restrict__ Fp, int N)
{
    const int node0 = (blockIdx.x / 3) * 16;
    const int pb    = (blockIdx.x % 3) * 3;
    const int lane  = threadIdx.x;
    const int row   = lane & 15, kg = lane >> 4;

    f16x8 a[4];
#pragma unroll
    for (int kt = 0; kt < 4; ++kt) {
        const float* p = &feat[(node0 + row) * IN_DIM + kt * 32 + kg * 8];
        const float4 fa = *(const float4*)p;
        const float4 fb = *(const float4*)(p + 4);
        f16x8 t = {(_Float16)fa.x, (_Float16)fa.y, (_Float16)fa.z,
                   (_Float16)fa.w, (_Float16)fb.x, (_Float16)fb.y,
                   (_Float16)fb.z, (_Float16)fb.w};
        a[kt] = t;
    }

#pragma unroll
    for (int pp = 0; pp < 3; ++pp) {
        const int p = pb + pp;                    // plane 0..8
        f32x4 cre = {0.f, 0.f, 0.f, 0.f};
        f32x4 cim = {0.f, 0.f, 0.f, 0.f};
#pragma unroll
        for (int kt = 0; kt < 4; ++kt) {
            const f16x8 bre =
                *(const f16x8*)&Bp[(((size_t)kt * NT + p) * 64 + lane) * 8];
            const f16x8 bim =
                *(const f16x8*)&Bp[(((size_t)kt * NT + p + 9) * 64 + lane) * 8];
            cre = __builtin_amdgcn_mfma_f32_16x16x32_f16(a[kt], bre, cre, 0, 0, 0);
            cim = __builtin_amdgcn_mfma_f32_16x16x32_f16(a[kt], bim, cim, 0, 0, 0);
        }
        const int e = p * 16 + row;
        const float br = bf[e], bi = bf[NE + e];
#pragma unroll
        for (int r = 0; r < 4; ++r) {
            const int node = node0 + kg * 4 + r;
            Fp[((size_t)p * N + node) * 16 + row] =
                __floats2half2_rn(cre[r] + br, cim[r] + bi);
        }
    }
}

// ---------------------------------------------------------------------------
// Gather + product, XCD-pinned planes. Grid 11250 x 64 threads.
// bid<10000: tile=bid>>3, gg=bid&7 (so gg == bid%8 -> same XCD per plane);
// bid>=10000: tile=bid-10000, gg=8.
// Lane = (node_l = lane>>2, sub = lane&3): loads 16 neighbors' 16B chunks
// from plane gg (random 64B rows, L2-resident per XCD), computes the
// 16-factor complex product for its 4 elements, stores one 16B bf16 chunk
// to Pg in MFMA-A k-chunk layout (k = 2e+ri).
// ---------------------------------------------------------------------------
__global__ __launch_bounds__(64) void k_gather(
    const int* __restrict__ nbr, const __half2* __restrict__ Fp,
    unsigned int* __restrict__ Pg, int N)
{
    const int bid = blockIdx.x;
    int t, gg;
    if (bid < 10000) { t = bid >> 3; gg = bid & 7; }
    else             { t = bid - 10000; gg = 8; }

    const int lane = threadIdx.x;
    const int nl = lane >> 2, sub = lane & 3;
    const int node = t * 16 + nl;

    const int4 n0 = *(const int4*)&nbr[node * KNBR + 0];
    const int4 n1 = *(const int4*)&nbr[node * KNBR + 4];
    const int4 n2 = *(const int4*)&nbr[node * KNBR + 8];
    const int4 n3 = *(const int4*)&nbr[node * KNBR + 12];
    const int nrow[16] = {n0.x, n0.y, n0.z, n0.w, n1.x, n1.y, n1.z, n1.w,
                          n2.x, n2.y, n2.z, n2.w, n3.x, n3.y, n3.z, n3.w};

    uint4 f[16];
#pragma unroll
    for (int k = 0; k < 16; ++k)
        f[k] = *(const uint4*)&Fp[((size_t)gg * N + nrow[k]) * 16 + sub * 4];

    uint4 outv;
#pragma unroll
    for (int j = 0; j < 4; ++j) {
        float2 c[16];
#pragma unroll
        for (int k = 0; k < 16; ++k) c[k] = h2f(u4c(f[k], j));
        float2 g[8];
#pragma unroll
        for (int k = 0; k < 8; ++k) g[k] = cmul(c[2 * k], c[2 * k + 1]);
#pragma unroll
        for (int k = 0; k < 4; ++k) g[k] = cmul(g[2 * k], g[2 * k + 1]);
        const float2 p = cmul(cmul(g[0], g[1]), cmul(g[2], g[3]));
        ((unsigned int*)&outv)[j] = packbf(p.x, p.y);
    }
    *(uint4*)&Pg[(((size_t)gg * 4 + sub) * N + node) * 4] = outv;
}

// ---------------------------------------------------------------------------
// Streaming MFMA MLP. 1250 blocks x 256 threads (4 waves), no LDS.
// Wave w owns cols [32w, 32w+32): 9 kt x (A from Pg, 2 B from Wp, 2 MFMA).
// ---------------------------------------------------------------------------
__global__ __launch_bounds__(256) void k_mlp(
    const unsigned int* __restrict__ Pg, const unsigned short* __restrict__ Wp,
    const float* __restrict__ b_mlp, float* __restrict__ out, int N)
{
    const int node0 = blockIdx.x * 16;
    const int tid  = threadIdx.x;
    const int lane = tid & 63;
    const int w    = __builtin_amdgcn_readfirstlane(tid >> 6);

    f32x4 c0 = {0.f, 0.f, 0.f, 0.f}, c1 = {0.f, 0.f, 0.f, 0.f};
#pragma unroll
    for (int kt = 0; kt < 9; ++kt) {
        const bf16x8 a = *(const bf16x8*)
            &Pg[(((size_t)kt * 4 + (lane >> 4)) * N + node0 + (lane & 15)) * 4];
        const bf16x8 b0 = *(const bf16x8*)
            &Wp[(((size_t)kt * 8 + (w * 2 + 0)) * 64 + lane) * 8];
        const bf16x8 b1 = *(const bf16x8*)
            &Wp[(((size_t)kt * 8 + (w * 2 + 1)) * 64 + lane) * 8];
        c0 = __builtin_amdgcn_mfma_f32_16x16x32_bf16(a, b0, c0, 0, 0, 0);
        c1 = __builtin_amdgcn_mfma_f32_16x16x32_bf16(a, b1, c1, 0, 0, 0);
    }

    const int col0 = (w * 2 + 0) * 16 + (lane & 15);
    const int col1 = (w * 2 + 1) * 16 + (lane & 15);
    const float bias0 = b_mlp[col0];
    const float bias1 = b_mlp[col1];
#pragma unroll
    for (int r = 0; r < 4; ++r) {
        const int row = (lane >> 4) * 4 + r;
        out[(node0 + row) * OUT_DIM + col0] = c0[r] + bias0;
        out[(node0 + row) * OUT_DIM + col1] = c1[r] + bias1;
    }
}

extern "C" void kernel_launch(void* const* d_in, const int* in_sizes, int n_in,
                              void* d_out, int out_size, void* d_ws, size_t ws_size,
                              hipStream_t stream) {
    const float* feature   = (const float*)d_in[0];
    const int*   neighbors = (const int*)d_in[1];
    const float* W_aff     = (const float*)d_in[2];
    const float* b_aff     = (const float*)d_in[3];
    const float* W_mlp     = (const float*)d_in[4];
    const float* b_mlp     = (const float*)d_in[5];
    float*       out       = (float*)d_out;

    const int N = in_sizes[0] / IN_DIM;   // 20000

    // workspace layout
    __half*         Bp = (__half*)d_ws;                   // 36864 halfs
    float*          bf = (float*)(Bp + 36864);            // 288 f32
    unsigned short* Wp = (unsigned short*)(bf + 288);     // 36864 bf16
    __half2*        Fp = (__half2*)(Wp + 36864);          // 9*N*16 half2 (11.5 MB)
    unsigned int*   Pg = (unsigned int*)(Fp + (size_t)9 * N * 16); // 36*N*4 u32 (11.5 MB)

    k_prep<<<273, 256, 0, stream>>>(W_aff, b_aff, W_mlp, Bp, bf, Wp);
    k_spectra_mfma<<<3750, 64, 0, stream>>>(feature, Bp, bf, Fp, N);
    k_gather<<<11250, 64, 0, stream>>>(neighbors, Fp, Pg, N);
    k_mlp<<<1250, 256, 0, stream>>>(Pg, Wp, b_mlp, out, N);
}